// Round 11
// baseline (496.711 us; speedup 1.0000x reference)
//
#include <hip/hip_runtime.h>
#include <hip/hip_fp16.h>

#define CCH 128      // FEATURE_DIM (channels)
#define NCP 25
#define HH  128      // plane H
#define WW  128      // plane W
#define NPIX (HH * WW)
#define NITER 2      // grid-stride halves (batch windowing)

// ------------- Transpose+convert (B,C,H,W) f32 -> (B,H,W,C) f16 -------------
__global__ __launch_bounds__(256) void transpose_f16_kernel(
    const float* __restrict__ s0, const float* __restrict__ s1, const float* __restrict__ s2,
    __half* __restrict__ d0, __half* __restrict__ d1, __half* __restrict__ d2)
{
    __shared__ float tile[64][65];
    const int z = blockIdx.z;           // b*3 + plane
    const int b = z / 3, pl = z - 3 * b;
    const float* src = (pl == 0 ? s0 : pl == 1 ? s1 : s2) + (size_t)b * CCH * NPIX;
    __half* dst      = (pl == 0 ? d0 : pl == 1 ? d1 : d2) + (size_t)b * CCH * NPIX;
    const int n0 = blockIdx.x * 64;
    const int c0 = blockIdx.y * 64;
    const int tx = threadIdx.x;         // 0..63
    const int ty = threadIdx.y;         // 0..3

    #pragma unroll
    for (int cc = 0; cc < 64; cc += 4)
        tile[cc + ty][tx] = src[(size_t)(c0 + cc + ty) * NPIX + (n0 + tx)];
    __syncthreads();
    #pragma unroll
    for (int nn = 0; nn < 64; nn += 4)
        dst[(size_t)(n0 + nn + ty) * CCH + (c0 + tx)] = __float2half(tile[tx][nn + ty]);
}

// ------------- sample helpers (channel-pair per lane) -----------------------
struct Ctx2 { int off; __half2 wxh, wyh; };  // off in __half2 units

__device__ __forceinline__ Ctx2 mkctx2(int lane, float u, float v) {
    float x = fminf(fmaxf(u, 0.f), 1.f) * 127.f;
    float y = fminf(fmaxf(v, 0.f), 1.f) * 127.f;
    int x0 = (int)floorf(x); x0 = x0 > 126 ? 126 : x0;
    int y0 = (int)floorf(y); y0 = y0 > 126 ? 126 : y0;
    Ctx2 c;
    c.wxh = __float2half2_rn(x - (float)x0);
    c.wyh = __float2half2_rn(y - (float)y0);
    c.off = (y0 * WW + x0) * 64 + lane;   // 64 half2 per pixel (128 ch)
    return c;
}

__device__ __forceinline__ __half2 samp2(const __half2* __restrict__ P, Ctx2 c) {
    __half2 f00 = P[c.off];
    __half2 f01 = P[c.off + 64];
    __half2 f10 = P[c.off + 8192];
    __half2 f11 = P[c.off + 8256];
    __half2 top = __hfma2(__hsub2(f01, f00), c.wxh, f00);
    __half2 bot = __hfma2(__hsub2(f11, f10), c.wxh, f10);
    return __hfma2(__hsub2(bot, top), c.wyh, top);
}

// ------------- Main fused kernel (R8 structure + 2-iteration windowing) -----
// Per iteration: 8 queries/block. Waves (2p,2p+1) co-own queries 4p..4p+3:
//   wave even: feature sample + anchors 0..11  -> sA
//   wave odd : anchors 12..24                  -> sB
// lane: qg = lane>>4 (query in group), cg = lane&15 (channels 8cg..8cg+7)
__global__ __launch_bounds__(256, 8) void equi_win_kernel(
    const float* __restrict__ qp,    // (bs, ns, 9)
    const __half* __restrict__ cxz,  // (bs, NPIX, C) f16
    const __half* __restrict__ cxy,
    const __half* __restrict__ cyz,
    const float* __restrict__ cp,    // (NCP, 3)
    const float* __restrict__ Wv,    // (C, HID)
    const float* __restrict__ bv,
    const float* __restrict__ Ww,    // (C, NCP)
    const float* __restrict__ bw,
    const float* __restrict__ Wo,    // (HID, C)
    const float* __restrict__ bo,
    float* __restrict__ out,         // (bs, ns, C)
    int ns, int qPerIter)
{
    // bijective XCD swizzle (within each iteration window)
    const int nwg = gridDim.x;
    const int bid = blockIdx.x;
    const int qq = nwg >> 3, rr = nwg & 7;
    const int xcd = bid & 7, loc = bid >> 3;
    const int swz = (xcd < rr ? xcd * (qq + 1) : rr * (qq + 1) + (xcd - rr) * qq) + loc;

    const int t    = threadIdx.x;
    const int w    = t >> 6;             // wave 0..3
    const int pair = w >> 1;             // 0,1
    const int half = w & 1;              // 0: feature+g<12, 1: g>=12
    const int lane = t & 63;
    const int qg   = lane >> 4;
    const int cg   = lane & 15;
    const int qloc = pair * 4 + qg;      // 0..7

    const size_t planeStride = (size_t)CCH * NPIX;

    __shared__ __align__(16) float sFeat[8][CCH];   // 4 KB
    __shared__ __align__(16) float sA[8][CCH];      // 4 KB
    __shared__ __align__(16) float sB[8][CCH];      // 4 KB
    __shared__ __align__(16) float sPre[8][CCH];    // 4 KB
    __shared__ float sW[8][28];
    __shared__ float sSw[8];

    // descending: iteration NITER-1 covers the last-transposed (cache-warm) batches
    for (int it = NITER - 1; it >= 0; --it) {
        const int q0 = it * qPerIter + swz * 8;      // first query of block this iter
        const int qglob = q0 + qloc;
        const int b = qglob / ns;

        const __half2* P0 = (const __half2*)(cxz + (size_t)b * planeStride);
        const __half2* P1 = (const __half2*)(cxy + (size_t)b * planeStride);
        const __half2* P2 = (const __half2*)(cyz + (size_t)b * planeStride);

        const float* qptr = qp + (size_t)qglob * 9;
        const float px = qptr[0], py = qptr[1], pz = qptr[2];
        const float a1x = qptr[3], a1y = qptr[4], a1z = qptr[5];
        const float a2x = qptr[6], a2y = qptr[7], a2z = qptr[8];

        // rot6d -> matrix (rows b1,b2,b3)
        float n1 = rsqrtf(a1x * a1x + a1y * a1y + a1z * a1z);
        float b1x = a1x * n1, b1y = a1y * n1, b1z = a1z * n1;
        float dd = b1x * a2x + b1y * a2y + b1z * a2z;
        float u2x = a2x - dd * b1x, u2y = a2y - dd * b1y, u2z = a2z - dd * b1z;
        float n2 = rsqrtf(u2x * u2x + u2y * u2y + u2z * u2z);
        float b2x = u2x * n2, b2y = u2y * n2, b2z = u2z * n2;
        float b3x = b1y * b2z - b1z * b2y;
        float b3y = b1z * b2x - b1x * b2z;
        float b3z = b1x * b2y - b1y * b2x;

        // ---- phase 1: feature sample (wave-half 0, lane covers 2 ch of q) ----
        if (half == 0) {
            // each of 16 lanes-per-query covers ch pair via qg? No: here lane
            // layout is (qg,cg): 16 lanes per query, each lane 8 channels via 4 half2
            // -> use 4 samples of half2 at cg*4 .. cg*4+3
            Ctx2 c0 = mkctx2(0, px, pz);
            Ctx2 c1 = mkctx2(0, px, py);
            Ctx2 c2 = mkctx2(0, py, pz);
            #pragma unroll
            for (int u = 0; u < 4; ++u) {
                const int ch2 = cg * 4 + u;          // half2 index 0..63
                Ctx2 d0 = c0; d0.off += ch2;
                Ctx2 d1 = c1; d1.off += ch2;
                Ctx2 d2 = c2; d2.off += ch2;
                __half2 s = __hadd2(__hadd2(samp2(P0, d0), samp2(P1, d1)), samp2(P2, d2));
                float2 f = __half22float2(s);
                sFeat[qloc][ch2 * 2]     = f.x;
                sFeat[qloc][ch2 * 2 + 1] = f.y;
            }
        }
        __syncthreads();

        // ---- phase 2: weights[q][g] = feat[q].Ww[:,g] + bw[g] (200 outputs) ----
        if (t < 8 * NCP) {
            int qi = t / NCP, g = t - qi * NCP;
            float acc = bw[g];
            #pragma unroll 8
            for (int c = 0; c < CCH; ++c)
                acc += sFeat[qi][c] * Ww[c * NCP + g];
            sW[qi][g] = acc;
        }
        __syncthreads();
        if (t < 8) {
            float s = 0.f;
            #pragma unroll
            for (int g = 0; g < NCP; ++g) s += sW[t][g];
            sSw[t] = s;
        }

        // ---- phase 3: anchor gather; wave halves split anchors 12/13 ----
        float acc8[8] = {0.f, 0.f, 0.f, 0.f, 0.f, 0.f, 0.f, 0.f};
        const int gbeg = half ? 12 : 0;
        const int gend = half ? 25 : 12;
        for (int g = gbeg; g < gend; ++g) {
            float cpx = cp[g * 3 + 0], cpy = cp[g * 3 + 1], cpz = cp[g * 3 + 2];
            float ax = px + b1x * cpx + b1y * cpy + b1z * cpz;
            float ay = py + b2x * cpx + b2y * cpy + b2z * cpz;
            float az = pz + b3x * cpx + b3y * cpy + b3z * cpz;
            Ctx2 c0 = mkctx2(0, ax, az);
            Ctx2 c1 = mkctx2(0, ax, ay);
            Ctx2 c2 = mkctx2(0, ay, az);
            float wg = sW[qloc][g];
            #pragma unroll
            for (int u = 0; u < 4; ++u) {
                const int ch2 = cg * 4 + u;
                Ctx2 d0 = c0; d0.off += ch2;
                Ctx2 d1 = c1; d1.off += ch2;
                Ctx2 d2 = c2; d2.off += ch2;
                __half2 s = __hadd2(__hadd2(samp2(P0, d0), samp2(P1, d1)), samp2(P2, d2));
                float2 f = __half22float2(s);
                acc8[2 * u]     += wg * f.x;
                acc8[2 * u + 1] += wg * f.y;
            }
        }
        {
            float* dst = (half ? &sB[qloc][cg * 8] : &sA[qloc][cg * 8]);
            *(float4*)dst       = make_float4(acc8[0], acc8[1], acc8[2], acc8[3]);
            *(float4*)(dst + 4) = make_float4(acc8[4], acc8[5], acc8[6], acc8[7]);
        }
        __syncthreads();

        // ---- phase 4: pre[q][h] = sSw[q]*bv[h] + sum_c (A+B)[q][c]*Wv[c][h] ----
        {
            const int qi = t >> 5;            // 0..7
            const int hs = (t & 31) * 4;      // 4 h-columns
            float4 bva = *(const float4*)&bv[hs];
            float sw = sSw[qi];
            float a0 = sw * bva.x, a1 = sw * bva.y, a2 = sw * bva.z, a3 = sw * bva.w;
            #pragma unroll 4
            for (int c = 0; c < CCH; ++c) {
                float4 wva = *(const float4*)&Wv[c * CCH + hs];
                float ws = sA[qi][c] + sB[qi][c];
                a0 += ws * wva.x; a1 += ws * wva.y; a2 += ws * wva.z; a3 += ws * wva.w;
            }
            *(float4*)&sPre[qi][hs] = make_float4(a0, a1, a2, a3);
        }
        __syncthreads();

        // ---- phase 5: out[q][c] = bo[c] + feat[q][c] + sum_h pre[q][h]*Wo[h][c] ----
        {
            const int qi = t >> 5;
            const int cs = (t & 31) * 4;
            float4 boa = *(const float4*)&bo[cs];
            float4 fta = *(const float4*)&sFeat[qi][cs];
            float a0 = boa.x + fta.x, a1 = boa.y + fta.y, a2 = boa.z + fta.z, a3 = boa.w + fta.w;
            #pragma unroll 4
            for (int h = 0; h < CCH; ++h) {
                float4 woa = *(const float4*)&Wo[h * CCH + cs];
                float ph = sPre[qi][h];
                a0 += ph * woa.x; a1 += ph * woa.y; a2 += ph * woa.z; a3 += ph * woa.w;
            }
            float* op = out + (size_t)(q0 + qi) * CCH + cs;
            *(float4*)op = make_float4(a0, a1, a2, a3);
        }
        __syncthreads();   // protect shared buffers before next iteration
    }
}

// ------------- Fallback (channel-first fp32, no workspace) ------------------
__device__ __forceinline__ float bilin_cf(const float* __restrict__ pl, int c, float u, float v) {
    float x = fminf(fmaxf(u, 0.f), 1.f) * (float)(WW - 1);
    float y = fminf(fmaxf(v, 0.f), 1.f) * (float)(HH - 1);
    int x0 = (int)floorf(x); x0 = x0 > (WW - 2) ? (WW - 2) : x0;
    int y0 = (int)floorf(y); y0 = y0 > (HH - 2) ? (HH - 2) : y0;
    float wx = x - (float)x0;
    float wy = y - (float)y0;
    const float* p = pl + ((size_t)c << 14) + (y0 << 7) + x0;
    float top = p[0] * (1.f - wx) + p[1] * wx;
    float bot = p[WW] * (1.f - wx) + p[WW + 1] * wx;
    return top * (1.f - wy) + bot * wy;
}

__global__ __launch_bounds__(128) void equi_attn_cf_kernel(
    const float* __restrict__ qp, const float* __restrict__ cxz,
    const float* __restrict__ cxy, const float* __restrict__ cyz,
    const float* __restrict__ cp, const float* __restrict__ Wv,
    const float* __restrict__ bv, const float* __restrict__ Ww,
    const float* __restrict__ bw, const float* __restrict__ Wo,
    const float* __restrict__ bo, float* __restrict__ out, int ns)
{
    const int q = blockIdx.x, b = q / ns, tid = threadIdx.x;
    const size_t planeStride = (size_t)CCH * NPIX;
    const float* pxz = cxz + (size_t)b * planeStride;
    const float* pxy = cxy + (size_t)b * planeStride;
    const float* pyz = cyz + (size_t)b * planeStride;
    const float* qptr = qp + (size_t)q * 9;
    const float px = qptr[0], py = qptr[1], pz = qptr[2];
    const float a1x = qptr[3], a1y = qptr[4], a1z = qptr[5];
    const float a2x = qptr[6], a2y = qptr[7], a2z = qptr[8];
    float n1 = rsqrtf(a1x * a1x + a1y * a1y + a1z * a1z);
    float b1x = a1x * n1, b1y = a1y * n1, b1z = a1z * n1;
    float dd = b1x * a2x + b1y * a2y + b1z * a2z;
    float u2x = a2x - dd * b1x, u2y = a2y - dd * b1y, u2z = a2z - dd * b1z;
    float n2 = rsqrtf(u2x * u2x + u2y * u2y + u2z * u2z);
    float b2x = u2x * n2, b2y = u2y * n2, b2z = u2z * n2;
    float b3x = b1y * b2z - b1z * b2y;
    float b3y = b1z * b2x - b1x * b2z;
    float b3z = b1x * b2y - b1y * b2x;
    __shared__ float sFeat[CCH]; __shared__ float sW[32];
    __shared__ float sWsum[CCH]; __shared__ float sPre[CCH];
    float feat = bilin_cf(pxz, tid, px, pz) + bilin_cf(pxy, tid, px, py) + bilin_cf(pyz, tid, py, pz);
    sFeat[tid] = feat;
    __syncthreads();
    if (tid < NCP) {
        float acc = bw[tid];
        for (int c = 0; c < CCH; ++c) acc += sFeat[c] * Ww[c * NCP + tid];
        sW[tid] = acc;
    }
    __syncthreads();
    float sw = 0.f;
    #pragma unroll
    for (int g = 0; g < NCP; ++g) sw += sW[g];
    float wacc = 0.f;
    for (int g = 0; g < NCP; ++g) {
        float cx = cp[g * 3 + 0], cy = cp[g * 3 + 1], cz = cp[g * 3 + 2];
        float ax = px + b1x * cx + b1y * cy + b1z * cz;
        float ay = py + b2x * cx + b2y * cy + b2z * cz;
        float az = pz + b3x * cx + b3y * cy + b3z * cz;
        wacc += sW[g] * (bilin_cf(pxz, tid, ax, az) + bilin_cf(pxy, tid, ax, ay) + bilin_cf(pyz, tid, ay, az));
    }
    sWsum[tid] = wacc;
    __syncthreads();
    float pre = sw * bv[tid];
    for (int c = 0; c < CCH; ++c) pre += sWsum[c] * Wv[c * CCH + tid];
    sPre[tid] = pre;
    __syncthreads();
    float o = bo[tid] + feat;
    for (int h = 0; h < CCH; ++h) o += sPre[h] * Wo[h * CCH + tid];
    out[(size_t)q * CCH + tid] = o;
}

extern "C" void kernel_launch(void* const* d_in, const int* in_sizes, int n_in,
                              void* d_out, int out_size, void* d_ws, size_t ws_size,
                              hipStream_t stream) {
    const float* qp  = (const float*)d_in[0];
    const float* cxz = (const float*)d_in[1];
    const float* cxy = (const float*)d_in[2];
    const float* cyz = (const float*)d_in[3];
    const float* cp  = (const float*)d_in[4];
    const float* Wv  = (const float*)d_in[5];
    const float* bv  = (const float*)d_in[6];
    const float* Ww  = (const float*)d_in[7];
    const float* bw  = (const float*)d_in[8];
    const float* Wo  = (const float*)d_in[9];
    const float* bo  = (const float*)d_in[10];
    float* out = (float*)d_out;

    const int bs = in_sizes[1] / (CCH * NPIX);
    const int ns = in_sizes[0] / (bs * 9);
    const int nq = bs * ns;

    const size_t planeFloats = (size_t)bs * CCH * NPIX;     // per plane
    const size_t needBytes = 3 * planeFloats * sizeof(__half);

    // need nq divisible by 8*NITER
    if (ws_size >= needBytes && (nq % (8 * NITER)) == 0) {
        __half* t_xz = (__half*)d_ws;
        __half* t_xy = t_xz + planeFloats;
        __half* t_yz = t_xy + planeFloats;

        dim3 tgrid(NPIX / 64, CCH / 64, bs * 3);
        dim3 tblk(64, 4);
        transpose_f16_kernel<<<tgrid, tblk, 0, stream>>>(cxz, cxy, cyz, t_xz, t_xy, t_yz);

        const int qPerIter = nq / NITER;
        const int nblk = qPerIter / 8;
        equi_win_kernel<<<nblk, 256, 0, stream>>>(
            qp, t_xz, t_xy, t_yz, cp, Wv, bv, Ww, bw, Wo, bo, out, ns, qPerIter);
    } else {
        equi_attn_cf_kernel<<<nq, 128, 0, stream>>>(
            qp, cxz, cxy, cyz, cp, Wv, bv, Ww, bw, Wo, bo, out, ns);
    }
}

// Round 12
// 299.392 us; speedup vs baseline: 1.6591x; 1.6591x over previous
//
#include <hip/hip_runtime.h>
#include <hip/hip_fp16.h>

#define CCH 128      // FEATURE_DIM (channels)
#define NCP 25
#define HH  128      // plane H
#define WW  128      // plane W
#define NPIX (HH * WW)

// ------------- Transpose+convert (B,C,H,W) f32 -> (B,H,W,C) f16 -------------
__global__ __launch_bounds__(256) void transpose_f16_kernel(
    const float* __restrict__ s0, const float* __restrict__ s1, const float* __restrict__ s2,
    __half* __restrict__ d0, __half* __restrict__ d1, __half* __restrict__ d2)
{
    __shared__ float tile[64][65];
    const int z = blockIdx.z;           // b*3 + plane
    const int b = z / 3, pl = z - 3 * b;
    const float* src = (pl == 0 ? s0 : pl == 1 ? s1 : s2) + (size_t)b * CCH * NPIX;
    __half* dst      = (pl == 0 ? d0 : pl == 1 ? d1 : d2) + (size_t)b * CCH * NPIX;
    const int n0 = blockIdx.x * 64;
    const int c0 = blockIdx.y * 64;
    const int tx = threadIdx.x;         // 0..63
    const int ty = threadIdx.y;         // 0..3

    #pragma unroll
    for (int cc = 0; cc < 64; cc += 4)
        tile[cc + ty][tx] = src[(size_t)(c0 + cc + ty) * NPIX + (n0 + tx)];
    __syncthreads();
    #pragma unroll
    for (int nn = 0; nn < 64; nn += 4)
        dst[(size_t)(n0 + nn + ty) * CCH + (c0 + tx)] = __float2half(tile[tx][nn + ty]);
}

// ------------- helpers ------------------------------------------------------
union F4H { float4 f; __half2 h[4]; };

struct Ctx { int off; __half2 wxh, wyh; };  // off in float4 units (pixel*16)

__device__ __forceinline__ Ctx mkctx(float u, float v) {
    float x = fminf(fmaxf(u, 0.f), 1.f) * 127.f;
    float y = fminf(fmaxf(v, 0.f), 1.f) * 127.f;
    int x0 = (int)floorf(x); x0 = x0 > 126 ? 126 : x0;
    int y0 = (int)floorf(y); y0 = y0 > 126 ? 126 : y0;
    Ctx c;
    c.wxh = __float2half2_rn(x - (float)x0);
    c.wyh = __float2half2_rn(y - (float)y0);
    c.off = (y0 * WW + x0) * 16;       // 16 float4 per pixel (128 halves)
    return c;
}

// bilinear over 4 half2 units; r[0]=f00 r[1]=f01 r[2]=f10 r[3]=f11
__device__ __forceinline__ void lerp4(const F4H* r, __half2 wx, __half2 wy, __half2 o[4]) {
    #pragma unroll
    for (int u = 0; u < 4; ++u) {
        __half2 top = __hfma2(__hsub2(r[1].h[u], r[0].h[u]), wx, r[0].h[u]);
        __half2 bot = __hfma2(__hsub2(r[3].h[u], r[2].h[u]), wx, r[2].h[u]);
        o[u] = __hfma2(__hsub2(bot, top), wy, top);
    }
}

// ------------- Main fused kernel: 4 queries per wave, 16 per block ----------
// lane: qg = lane>>4 (query in wave), cg = lane&15 (channel group: ch 8cg..8cg+7)
__global__ __launch_bounds__(256, 4) void equi_qpw4_kernel(
    const float* __restrict__ qp,    // (bs, ns, 9)
    const __half* __restrict__ cxz,  // (bs, NPIX, C) f16
    const __half* __restrict__ cxy,
    const __half* __restrict__ cyz,
    const float* __restrict__ cp,    // (NCP, 3)
    const float* __restrict__ Wv,    // (C, HID)
    const float* __restrict__ bv,
    const float* __restrict__ Ww,    // (C, NCP)
    const float* __restrict__ bw,
    const float* __restrict__ Wo,    // (HID, C)
    const float* __restrict__ bo,
    float* __restrict__ out,         // (bs, ns, C)
    int ns)
{
    // bijective XCD swizzle: consecutive hardware XCDs get contiguous block chunks
    const int nwg = gridDim.x;
    const int bid = blockIdx.x;
    const int qq = nwg >> 3, rr = nwg & 7;
    const int xcd = bid & 7, loc = bid >> 3;
    const int swz = (xcd < rr ? xcd * (qq + 1) : rr * (qq + 1) + (xcd - rr) * qq) + loc;

    const int q0   = swz * 16;           // first query of block
    const int t    = threadIdx.x;
    const int w    = t >> 6;
    const int lane = t & 63;
    const int qg   = lane >> 4;
    const int cg   = lane & 15;
    const int qloc = w * 4 + qg;         // 0..15
    const int qglob = q0 + qloc;
    const int b    = qglob / ns;

    const size_t planeStride = (size_t)CCH * NPIX;
    const float4* P0 = (const float4*)(cxz + (size_t)b * planeStride) + cg;
    const float4* P1 = (const float4*)(cxy + (size_t)b * planeStride) + cg;
    const float4* P2 = (const float4*)(cyz + (size_t)b * planeStride) + cg;

    const float* qptr = qp + (size_t)qglob * 9;
    const float px = qptr[0], py = qptr[1], pz = qptr[2];
    const float a1x = qptr[3], a1y = qptr[4], a1z = qptr[5];
    const float a2x = qptr[6], a2y = qptr[7], a2z = qptr[8];

    // rot6d -> matrix (rows b1,b2,b3)
    float n1 = rsqrtf(a1x * a1x + a1y * a1y + a1z * a1z);
    float b1x = a1x * n1, b1y = a1y * n1, b1z = a1z * n1;
    float dd = b1x * a2x + b1y * a2y + b1z * a2z;
    float u2x = a2x - dd * b1x, u2y = a2y - dd * b1y, u2z = a2z - dd * b1z;
    float n2 = rsqrtf(u2x * u2x + u2y * u2y + u2z * u2z);
    float b2x = u2x * n2, b2y = u2y * n2, b2z = u2z * n2;
    float b3x = b1y * b2z - b1z * b2y;
    float b3y = b1z * b2x - b1x * b2z;
    float b3z = b1x * b2y - b1y * b2x;

    __shared__ __align__(16) float sFeat[16][CCH];
    __shared__ __align__(16) float sWsum[16][CCH];
    __shared__ __align__(16) float sPre[16][CCH];
    __shared__ float sW[16][28];
    __shared__ float sSw[16];

    // ---- phase 1: feature sample (each lane: 8 channels of its query) ----
    {
        Ctx c0 = mkctx(px, pz), c1 = mkctx(px, py), c2 = mkctx(py, pz);
        F4H r[12];
        r[0].f = P0[c0.off];  r[1].f = P0[c0.off + 16];  r[2].f = P0[c0.off + 2048];  r[3].f = P0[c0.off + 2064];
        r[4].f = P1[c1.off];  r[5].f = P1[c1.off + 16];  r[6].f = P1[c1.off + 2048];  r[7].f = P1[c1.off + 2064];
        r[8].f = P2[c2.off];  r[9].f = P2[c2.off + 16];  r[10].f = P2[c2.off + 2048]; r[11].f = P2[c2.off + 2064];
        __half2 s0[4], s1[4], s2[4];
        lerp4(&r[0], c0.wxh, c0.wyh, s0);
        lerp4(&r[4], c1.wxh, c1.wyh, s1);
        lerp4(&r[8], c2.wxh, c2.wyh, s2);
        float4 fa, fb;
        {
            __half2 u0 = __hadd2(__hadd2(s0[0], s1[0]), s2[0]);
            __half2 u1 = __hadd2(__hadd2(s0[1], s1[1]), s2[1]);
            __half2 u2 = __hadd2(__hadd2(s0[2], s1[2]), s2[2]);
            __half2 u3 = __hadd2(__hadd2(s0[3], s1[3]), s2[3]);
            float2 f0 = __half22float2(u0), f1 = __half22float2(u1);
            float2 f2 = __half22float2(u2), f3 = __half22float2(u3);
            fa = make_float4(f0.x, f0.y, f1.x, f1.y);
            fb = make_float4(f2.x, f2.y, f3.x, f3.y);
        }
        *(float4*)&sFeat[qloc][cg * 8]     = fa;
        *(float4*)&sFeat[qloc][cg * 8 + 4] = fb;
    }
    __syncthreads();

    // ---- phase 2: weights[q][g] = feat[q].Ww[:,g] + bw[g]  (400 outputs) ----
    #pragma unroll
    for (int rep = 0; rep < 2; ++rep) {
        int o = t + rep * 256;
        if (o < 16 * NCP) {
            int qi = o / NCP, g = o - qi * NCP;
            float acc = bw[g];
            #pragma unroll 8
            for (int c = 0; c < CCH; ++c)
                acc += sFeat[qi][c] * Ww[c * NCP + g];
            sW[qi][g] = acc;
        }
    }
    __syncthreads();
    if (t < 16) {
        float s = 0.f;
        #pragma unroll
        for (int g = 0; g < NCP; ++g) s += sW[t][g];
        sSw[t] = s;
    }

    // ---- phase 3: anchor gather (each lane: 8 ch of its query, 25 anchors) ----
    float acc8[8] = {0.f, 0.f, 0.f, 0.f, 0.f, 0.f, 0.f, 0.f};
    for (int g = 0; g < NCP; ++g) {
        float cpx = cp[g * 3 + 0], cpy = cp[g * 3 + 1], cpz = cp[g * 3 + 2];
        float ax = px + b1x * cpx + b1y * cpy + b1z * cpz;
        float ay = py + b2x * cpx + b2y * cpy + b2z * cpz;
        float az = pz + b3x * cpx + b3y * cpy + b3z * cpz;
        Ctx c0 = mkctx(ax, az), c1 = mkctx(ax, ay), c2 = mkctx(ay, az);
        F4H r[12];
        r[0].f = P0[c0.off];  r[1].f = P0[c0.off + 16];  r[2].f = P0[c0.off + 2048];  r[3].f = P0[c0.off + 2064];
        r[4].f = P1[c1.off];  r[5].f = P1[c1.off + 16];  r[6].f = P1[c1.off + 2048];  r[7].f = P1[c1.off + 2064];
        r[8].f = P2[c2.off];  r[9].f = P2[c2.off + 16];  r[10].f = P2[c2.off + 2048]; r[11].f = P2[c2.off + 2064];
        __half2 s0[4], s1[4], s2[4];
        lerp4(&r[0], c0.wxh, c0.wyh, s0);
        lerp4(&r[4], c1.wxh, c1.wyh, s1);
        lerp4(&r[8], c2.wxh, c2.wyh, s2);
        float wg = sW[qloc][g];
        #pragma unroll
        for (int u = 0; u < 4; ++u) {
            __half2 su = __hadd2(__hadd2(s0[u], s1[u]), s2[u]);
            float2 f = __half22float2(su);
            acc8[2 * u]     += wg * f.x;
            acc8[2 * u + 1] += wg * f.y;
        }
    }
    *(float4*)&sWsum[qloc][cg * 8]     = make_float4(acc8[0], acc8[1], acc8[2], acc8[3]);
    *(float4*)&sWsum[qloc][cg * 8 + 4] = make_float4(acc8[4], acc8[5], acc8[6], acc8[7]);
    __syncthreads();

    // ---- phase 4: pre[q][h] = sSw[q]*bv[h] + sum_c wsum[q][c]*Wv[c][h] ----
    {
        const int qi = t >> 4;            // 0..15
        const int hs = (t & 15) * 8;      // 8 h-columns
        float4 bva = *(const float4*)&bv[hs];
        float4 bvb = *(const float4*)&bv[hs + 4];
        float sw = sSw[qi];
        float a0 = sw * bva.x, a1 = sw * bva.y, a2 = sw * bva.z, a3 = sw * bva.w;
        float a4 = sw * bvb.x, a5 = sw * bvb.y, a6 = sw * bvb.z, a7 = sw * bvb.w;
        #pragma unroll 4
        for (int c = 0; c < CCH; ++c) {
            float4 wva = *(const float4*)&Wv[c * CCH + hs];
            float4 wvb = *(const float4*)&Wv[c * CCH + hs + 4];
            float ws = sWsum[qi][c];
            a0 += ws * wva.x; a1 += ws * wva.y; a2 += ws * wva.z; a3 += ws * wva.w;
            a4 += ws * wvb.x; a5 += ws * wvb.y; a6 += ws * wvb.z; a7 += ws * wvb.w;
        }
        *(float4*)&sPre[qi][hs]     = make_float4(a0, a1, a2, a3);
        *(float4*)&sPre[qi][hs + 4] = make_float4(a4, a5, a6, a7);
    }
    __syncthreads();

    // ---- phase 5: out[q][c] = bo[c] + feat[q][c] + sum_h pre[q][h]*Wo[h][c] ----
    {
        const int qi = t >> 4;
        const int cs = (t & 15) * 8;
        float4 boa = *(const float4*)&bo[cs];
        float4 bob = *(const float4*)&bo[cs + 4];
        float4 fta = *(const float4*)&sFeat[qi][cs];
        float4 ftb = *(const float4*)&sFeat[qi][cs + 4];
        float a0 = boa.x + fta.x, a1 = boa.y + fta.y, a2 = boa.z + fta.z, a3 = boa.w + fta.w;
        float a4 = bob.x + ftb.x, a5 = bob.y + ftb.y, a6 = bob.z + ftb.z, a7 = bob.w + ftb.w;
        #pragma unroll 4
        for (int h = 0; h < CCH; ++h) {
            float4 woa = *(const float4*)&Wo[h * CCH + cs];
            float4 wob = *(const float4*)&Wo[h * CCH + cs + 4];
            float ph = sPre[qi][h];
            a0 += ph * woa.x; a1 += ph * woa.y; a2 += ph * woa.z; a3 += ph * woa.w;
            a4 += ph * wob.x; a5 += ph * wob.y; a6 += ph * wob.z; a7 += ph * wob.w;
        }
        float* op = out + (size_t)(q0 + qi) * CCH + cs;
        *(float4*)op       = make_float4(a0, a1, a2, a3);
        *(float4*)(op + 4) = make_float4(a4, a5, a6, a7);
    }
}

// ------------- Fallback (channel-first fp32, no workspace) ------------------
__device__ __forceinline__ float bilin_cf(const float* __restrict__ pl, int c, float u, float v) {
    float x = fminf(fmaxf(u, 0.f), 1.f) * (float)(WW - 1);
    float y = fminf(fmaxf(v, 0.f), 1.f) * (float)(HH - 1);
    int x0 = (int)floorf(x); x0 = x0 > (WW - 2) ? (WW - 2) : x0;
    int y0 = (int)floorf(y); y0 = y0 > (HH - 2) ? (HH - 2) : y0;
    float wx = x - (float)x0;
    float wy = y - (float)y0;
    const float* p = pl + ((size_t)c << 14) + (y0 << 7) + x0;
    float top = p[0] * (1.f - wx) + p[1] * wx;
    float bot = p[WW] * (1.f - wx) + p[WW + 1] * wx;
    return top * (1.f - wy) + bot * wy;
}

__global__ __launch_bounds__(128) void equi_attn_cf_kernel(
    const float* __restrict__ qp, const float* __restrict__ cxz,
    const float* __restrict__ cxy, const float* __restrict__ cyz,
    const float* __restrict__ cp, const float* __restrict__ Wv,
    const float* __restrict__ bv, const float* __restrict__ Ww,
    const float* __restrict__ bw, const float* __restrict__ Wo,
    const float* __restrict__ bo, float* __restrict__ out, int ns)
{
    const int q = blockIdx.x, b = q / ns, tid = threadIdx.x;
    const size_t planeStride = (size_t)CCH * NPIX;
    const float* pxz = cxz + (size_t)b * planeStride;
    const float* pxy = cxy + (size_t)b * planeStride;
    const float* pyz = cyz + (size_t)b * planeStride;
    const float* qptr = qp + (size_t)q * 9;
    const float px = qptr[0], py = qptr[1], pz = qptr[2];
    const float a1x = qptr[3], a1y = qptr[4], a1z = qptr[5];
    const float a2x = qptr[6], a2y = qptr[7], a2z = qptr[8];
    float n1 = rsqrtf(a1x * a1x + a1y * a1y + a1z * a1z);
    float b1x = a1x * n1, b1y = a1y * n1, b1z = a1z * n1;
    float dd = b1x * a2x + b1y * a2y + b1z * a2z;
    float u2x = a2x - dd * b1x, u2y = a2y - dd * b1y, u2z = a2z - dd * b1z;
    float n2 = rsqrtf(u2x * u2x + u2y * u2y + u2z * u2z);
    float b2x = u2x * n2, b2y = u2y * n2, b2z = u2z * n2;
    float b3x = b1y * b2z - b1z * b2y;
    float b3y = b1z * b2x - b1x * b2z;
    float b3z = b1x * b2y - b1y * b2x;
    __shared__ float sFeat[CCH]; __shared__ float sW[32];
    __shared__ float sWsum[CCH]; __shared__ float sPre[CCH];
    float feat = bilin_cf(pxz, tid, px, pz) + bilin_cf(pxy, tid, px, py) + bilin_cf(pyz, tid, py, pz);
    sFeat[tid] = feat;
    __syncthreads();
    if (tid < NCP) {
        float acc = bw[tid];
        for (int c = 0; c < CCH; ++c) acc += sFeat[c] * Ww[c * NCP + tid];
        sW[tid] = acc;
    }
    __syncthreads();
    float sw = 0.f;
    #pragma unroll
    for (int g = 0; g < NCP; ++g) sw += sW[g];
    float wacc = 0.f;
    for (int g = 0; g < NCP; ++g) {
        float cx = cp[g * 3 + 0], cy = cp[g * 3 + 1], cz = cp[g * 3 + 2];
        float ax = px + b1x * cx + b1y * cy + b1z * cz;
        float ay = py + b2x * cx + b2y * cy + b2z * cz;
        float az = pz + b3x * cx + b3y * cy + b3z * cz;
        wacc += sW[g] * (bilin_cf(pxz, tid, ax, az) + bilin_cf(pxy, tid, ax, ay) + bilin_cf(pyz, tid, ay, az));
    }
    sWsum[tid] = wacc;
    __syncthreads();
    float pre = sw * bv[tid];
    for (int c = 0; c < CCH; ++c) pre += sWsum[c] * Wv[c * CCH + tid];
    sPre[tid] = pre;
    __syncthreads();
    float o = bo[tid] + feat;
    for (int h = 0; h < CCH; ++h) o += sPre[h] * Wo[h * CCH + tid];
    out[(size_t)q * CCH + tid] = o;
}

extern "C" void kernel_launch(void* const* d_in, const int* in_sizes, int n_in,
                              void* d_out, int out_size, void* d_ws, size_t ws_size,
                              hipStream_t stream) {
    const float* qp  = (const float*)d_in[0];
    const float* cxz = (const float*)d_in[1];
    const float* cxy = (const float*)d_in[2];
    const float* cyz = (const float*)d_in[3];
    const float* cp  = (const float*)d_in[4];
    const float* Wv  = (const float*)d_in[5];
    const float* bv  = (const float*)d_in[6];
    const float* Ww  = (const float*)d_in[7];
    const float* bw  = (const float*)d_in[8];
    const float* Wo  = (const float*)d_in[9];
    const float* bo  = (const float*)d_in[10];
    float* out = (float*)d_out;

    const int bs = in_sizes[1] / (CCH * NPIX);
    const int ns = in_sizes[0] / (bs * 9);
    const int nq = bs * ns;

    const size_t planeFloats = (size_t)bs * CCH * NPIX;     // per plane
    const size_t needBytes = 3 * planeFloats * sizeof(__half);

    if (ws_size >= needBytes && (nq % 16) == 0) {
        __half* t_xz = (__half*)d_ws;
        __half* t_xy = t_xz + planeFloats;
        __half* t_yz = t_xy + planeFloats;

        dim3 tgrid(NPIX / 64, CCH / 64, bs * 3);
        dim3 tblk(64, 4);
        transpose_f16_kernel<<<tgrid, tblk, 0, stream>>>(cxz, cxy, cyz, t_xz, t_xy, t_yz);

        equi_qpw4_kernel<<<nq / 16, 256, 0, stream>>>(
            qp, t_xz, t_xy, t_yz, cp, Wv, bv, Ww, bw, Wo, bo, out, ns);
    } else {
        equi_attn_cf_kernel<<<nq, 128, 0, stream>>>(
            qp, cxz, cxy, cyz, cp, Wv, bv, Ww, bw, Wo, bo, out, ns);
    }
}

// Round 14
// 298.549 us; speedup vs baseline: 1.6638x; 1.0028x over previous
//
#include <hip/hip_runtime.h>
#include <hip/hip_fp16.h>

#define CCH 128      // FEATURE_DIM (channels)
#define NCP 25
#define HH  128      // plane H
#define WW  128      // plane W
#define NPIX (HH * WW)

// ------------- Transpose+convert (B,C,H,W) f32 -> (B,H,W,C) f16 -------------
__global__ __launch_bounds__(256) void transpose_f16_kernel(
    const float* __restrict__ s0, const float* __restrict__ s1, const float* __restrict__ s2,
    __half* __restrict__ d0, __half* __restrict__ d1, __half* __restrict__ d2)
{
    __shared__ float tile[64][65];
    const int z = blockIdx.z;           // b*3 + plane
    const int b = z / 3, pl = z - 3 * b;
    const float* src = (pl == 0 ? s0 : pl == 1 ? s1 : s2) + (size_t)b * CCH * NPIX;
    __half* dst      = (pl == 0 ? d0 : pl == 1 ? d1 : d2) + (size_t)b * CCH * NPIX;
    const int n0 = blockIdx.x * 64;
    const int c0 = blockIdx.y * 64;
    const int tx = threadIdx.x;         // 0..63
    const int ty = threadIdx.y;         // 0..3

    #pragma unroll
    for (int cc = 0; cc < 64; cc += 4)
        tile[cc + ty][tx] = src[(size_t)(c0 + cc + ty) * NPIX + (n0 + tx)];
    __syncthreads();
    #pragma unroll
    for (int nn = 0; nn < 64; nn += 4)
        dst[(size_t)(n0 + nn + ty) * CCH + (c0 + tx)] = __float2half(tile[tx][nn + ty]);
}

// ------------- helpers ------------------------------------------------------
union F4H { float4 f; __half2 h[4]; };

struct Ctx { int off; __half2 wxh, wyh; };  // off in float4 units (pixel*16)

__device__ __forceinline__ Ctx mkctx(float u, float v) {
    float x = fminf(fmaxf(u, 0.f), 1.f) * 127.f;
    float y = fminf(fmaxf(v, 0.f), 1.f) * 127.f;
    int x0 = (int)floorf(x); x0 = x0 > 126 ? 126 : x0;
    int y0 = (int)floorf(y); y0 = y0 > 126 ? 126 : y0;
    Ctx c;
    c.wxh = __float2half2_rn(x - (float)x0);
    c.wyh = __float2half2_rn(y - (float)y0);
    c.off = (y0 * WW + x0) * 16;       // 16 float4 per pixel (128 halves)
    return c;
}

// bilinear over 4 half2 units; r[0]=f00 r[1]=f01 r[2]=f10 r[3]=f11
__device__ __forceinline__ void lerp4(const F4H* r, __half2 wx, __half2 wy, __half2 o[4]) {
    #pragma unroll
    for (int u = 0; u < 4; ++u) {
        __half2 top = __hfma2(__hsub2(r[1].h[u], r[0].h[u]), wx, r[0].h[u]);
        __half2 bot = __hfma2(__hsub2(r[3].h[u], r[2].h[u]), wx, r[2].h[u]);
        o[u] = __hfma2(__hsub2(bot, top), wy, top);
    }
}

// ------------- Main fused kernel: 4 queries per wave, 16 per block ----------
// lane: qg = lane>>4 (query in wave), cg = lane&15 (channel group: ch 8cg..8cg+7)
__global__ __launch_bounds__(256, 4) void equi_qpw4_kernel(
    const float* __restrict__ qp,    // (bs, ns, 9)
    const __half* __restrict__ cxz,  // (bs, NPIX, C) f16
    const __half* __restrict__ cxy,
    const __half* __restrict__ cyz,
    const float* __restrict__ cp,    // (NCP, 3)
    const float* __restrict__ Wv,    // (C, HID)
    const float* __restrict__ bv,
    const float* __restrict__ Ww,    // (C, NCP)
    const float* __restrict__ bw,
    const float* __restrict__ Wo,    // (HID, C)
    const float* __restrict__ bo,
    float* __restrict__ out,         // (bs, ns, C)
    int ns)
{
    // bijective XCD swizzle: consecutive hardware XCDs get contiguous block chunks
    const int nwg = gridDim.x;
    const int bid = blockIdx.x;
    const int qq = nwg >> 3, rr = nwg & 7;
    const int xcd = bid & 7, loc = bid >> 3;
    const int swz = (xcd < rr ? xcd * (qq + 1) : rr * (qq + 1) + (xcd - rr) * qq) + loc;

    const int q0   = swz * 16;           // first query of block
    const int t    = threadIdx.x;
    const int w    = t >> 6;
    const int lane = t & 63;
    const int qg   = lane >> 4;
    const int cg   = lane & 15;
    const int qloc = w * 4 + qg;         // 0..15
    const int qglob = q0 + qloc;
    const int b    = qglob / ns;

    const size_t planeStride = (size_t)CCH * NPIX;
    const float4* P0 = (const float4*)(cxz + (size_t)b * planeStride) + cg;
    const float4* P1 = (const float4*)(cxy + (size_t)b * planeStride) + cg;
    const float4* P2 = (const float4*)(cyz + (size_t)b * planeStride) + cg;

    const float* qptr = qp + (size_t)qglob * 9;
    const float px = qptr[0], py = qptr[1], pz = qptr[2];
    const float a1x = qptr[3], a1y = qptr[4], a1z = qptr[5];
    const float a2x = qptr[6], a2y = qptr[7], a2z = qptr[8];

    // rot6d -> matrix (rows b1,b2,b3)
    float n1 = rsqrtf(a1x * a1x + a1y * a1y + a1z * a1z);
    float b1x = a1x * n1, b1y = a1y * n1, b1z = a1z * n1;
    float dd = b1x * a2x + b1y * a2y + b1z * a2z;
    float u2x = a2x - dd * b1x, u2y = a2y - dd * b1y, u2z = a2z - dd * b1z;
    float n2 = rsqrtf(u2x * u2x + u2y * u2y + u2z * u2z);
    float b2x = u2x * n2, b2y = u2y * n2, b2z = u2z * n2;
    float b3x = b1y * b2z - b1z * b2y;
    float b3y = b1z * b2x - b1x * b2z;
    float b3z = b1x * b2y - b1y * b2x;

    __shared__ __align__(16) float sFeat[16][CCH];
    __shared__ __align__(16) float sWsum[16][CCH];
    __shared__ __align__(16) float sPre[16][CCH];
    __shared__ float sW[16][28];
    __shared__ float sSw[16];

    // ---- phase 1: feature sample (each lane: 8 channels of its query) ----
    {
        Ctx c0 = mkctx(px, pz), c1 = mkctx(px, py), c2 = mkctx(py, pz);
        F4H r[12];
        r[0].f = P0[c0.off];  r[1].f = P0[c0.off + 16];  r[2].f = P0[c0.off + 2048];  r[3].f = P0[c0.off + 2064];
        r[4].f = P1[c1.off];  r[5].f = P1[c1.off + 16];  r[6].f = P1[c1.off + 2048];  r[7].f = P1[c1.off + 2064];
        r[8].f = P2[c2.off];  r[9].f = P2[c2.off + 16];  r[10].f = P2[c2.off + 2048]; r[11].f = P2[c2.off + 2064];
        __half2 s0[4], s1[4], s2[4];
        lerp4(&r[0], c0.wxh, c0.wyh, s0);
        lerp4(&r[4], c1.wxh, c1.wyh, s1);
        lerp4(&r[8], c2.wxh, c2.wyh, s2);
        float4 fa, fb;
        {
            __half2 u0 = __hadd2(__hadd2(s0[0], s1[0]), s2[0]);
            __half2 u1 = __hadd2(__hadd2(s0[1], s1[1]), s2[1]);
            __half2 u2 = __hadd2(__hadd2(s0[2], s1[2]), s2[2]);
            __half2 u3 = __hadd2(__hadd2(s0[3], s1[3]), s2[3]);
            float2 f0 = __half22float2(u0), f1 = __half22float2(u1);
            float2 f2 = __half22float2(u2), f3 = __half22float2(u3);
            fa = make_float4(f0.x, f0.y, f1.x, f1.y);
            fb = make_float4(f2.x, f2.y, f3.x, f3.y);
        }
        *(float4*)&sFeat[qloc][cg * 8]     = fa;
        *(float4*)&sFeat[qloc][cg * 8 + 4] = fb;
    }
    __syncthreads();

    // ---- phase 2: weights[q][g] = feat[q].Ww[:,g] + bw[g]  (400 outputs) ----
    #pragma unroll
    for (int rep = 0; rep < 2; ++rep) {
        int o = t + rep * 256;
        if (o < 16 * NCP) {
            int qi = o / NCP, g = o - qi * NCP;
            float acc = bw[g];
            #pragma unroll 8
            for (int c = 0; c < CCH; ++c)
                acc += sFeat[qi][c] * Ww[c * NCP + g];
            sW[qi][g] = acc;
        }
    }
    __syncthreads();
    if (t < 16) {
        float s = 0.f;
        #pragma unroll
        for (int g = 0; g < NCP; ++g) s += sW[t][g];
        sSw[t] = s;
    }

    // ---- phase 3: anchor gather (each lane: 8 ch of its query, 25 anchors) ----
    float acc8[8] = {0.f, 0.f, 0.f, 0.f, 0.f, 0.f, 0.f, 0.f};
    for (int g = 0; g < NCP; ++g) {
        float cpx = cp[g * 3 + 0], cpy = cp[g * 3 + 1], cpz = cp[g * 3 + 2];
        float ax = px + b1x * cpx + b1y * cpy + b1z * cpz;
        float ay = py + b2x * cpx + b2y * cpy + b2z * cpz;
        float az = pz + b3x * cpx + b3y * cpy + b3z * cpz;
        Ctx c0 = mkctx(ax, az), c1 = mkctx(ax, ay), c2 = mkctx(ay, az);
        F4H r[12];
        r[0].f = P0[c0.off];  r[1].f = P0[c0.off + 16];  r[2].f = P0[c0.off + 2048];  r[3].f = P0[c0.off + 2064];
        r[4].f = P1[c1.off];  r[5].f = P1[c1.off + 16];  r[6].f = P1[c1.off + 2048];  r[7].f = P1[c1.off + 2064];
        r[8].f = P2[c2.off];  r[9].f = P2[c2.off + 16];  r[10].f = P2[c2.off + 2048]; r[11].f = P2[c2.off + 2064];
        __half2 s0[4], s1[4], s2[4];
        lerp4(&r[0], c0.wxh, c0.wyh, s0);
        lerp4(&r[4], c1.wxh, c1.wyh, s1);
        lerp4(&r[8], c2.wxh, c2.wyh, s2);
        float wg = sW[qloc][g];
        #pragma unroll
        for (int u = 0; u < 4; ++u) {
            __half2 su = __hadd2(__hadd2(s0[u], s1[u]), s2[u]);
            float2 f = __half22float2(su);
            acc8[2 * u]     += wg * f.x;
            acc8[2 * u + 1] += wg * f.y;
        }
    }
    *(float4*)&sWsum[qloc][cg * 8]     = make_float4(acc8[0], acc8[1], acc8[2], acc8[3]);
    *(float4*)&sWsum[qloc][cg * 8 + 4] = make_float4(acc8[4], acc8[5], acc8[6], acc8[7]);
    __syncthreads();

    // ---- phase 4: pre[q][h] = sSw[q]*bv[h] + sum_c wsum[q][c]*Wv[c][h] ----
    {
        const int qi = t >> 4;            // 0..15
        const int hs = (t & 15) * 8;      // 8 h-columns
        float4 bva = *(const float4*)&bv[hs];
        float4 bvb = *(const float4*)&bv[hs + 4];
        float sw = sSw[qi];
        float a0 = sw * bva.x, a1 = sw * bva.y, a2 = sw * bva.z, a3 = sw * bva.w;
        float a4 = sw * bvb.x, a5 = sw * bvb.y, a6 = sw * bvb.z, a7 = sw * bvb.w;
        #pragma unroll 4
        for (int c = 0; c < CCH; ++c) {
            float4 wva = *(const float4*)&Wv[c * CCH + hs];
            float4 wvb = *(const float4*)&Wv[c * CCH + hs + 4];
            float ws = sWsum[qi][c];
            a0 += ws * wva.x; a1 += ws * wva.y; a2 += ws * wva.z; a3 += ws * wva.w;
            a4 += ws * wvb.x; a5 += ws * wvb.y; a6 += ws * wvb.z; a7 += ws * wvb.w;
        }
        *(float4*)&sPre[qi][hs]     = make_float4(a0, a1, a2, a3);
        *(float4*)&sPre[qi][hs + 4] = make_float4(a4, a5, a6, a7);
    }
    __syncthreads();

    // ---- phase 5: out[q][c] = bo[c] + feat[q][c] + sum_h pre[q][h]*Wo[h][c] ----
    {
        const int qi = t >> 4;
        const int cs = (t & 15) * 8;
        float4 boa = *(const float4*)&bo[cs];
        float4 bob = *(const float4*)&bo[cs + 4];
        float4 fta = *(const float4*)&sFeat[qi][cs];
        float4 ftb = *(const float4*)&sFeat[qi][cs + 4];
        float a0 = boa.x + fta.x, a1 = boa.y + fta.y, a2 = boa.z + fta.z, a3 = boa.w + fta.w;
        float a4 = bob.x + ftb.x, a5 = bob.y + ftb.y, a6 = bob.z + ftb.z, a7 = bob.w + ftb.w;
        #pragma unroll 4
        for (int h = 0; h < CCH; ++h) {
            float4 woa = *(const float4*)&Wo[h * CCH + cs];
            float4 wob = *(const float4*)&Wo[h * CCH + cs + 4];
            float ph = sPre[qi][h];
            a0 += ph * woa.x; a1 += ph * woa.y; a2 += ph * woa.z; a3 += ph * woa.w;
            a4 += ph * wob.x; a5 += ph * wob.y; a6 += ph * wob.z; a7 += ph * wob.w;
        }
        float* op = out + (size_t)(q0 + qi) * CCH + cs;
        *(float4*)op       = make_float4(a0, a1, a2, a3);
        *(float4*)(op + 4) = make_float4(a4, a5, a6, a7);
    }
}

// ------------- Fallback (channel-first fp32, no workspace) ------------------
__device__ __forceinline__ float bilin_cf(const float* __restrict__ pl, int c, float u, float v) {
    float x = fminf(fmaxf(u, 0.f), 1.f) * (float)(WW - 1);
    float y = fminf(fmaxf(v, 0.f), 1.f) * (float)(HH - 1);
    int x0 = (int)floorf(x); x0 = x0 > (WW - 2) ? (WW - 2) : x0;
    int y0 = (int)floorf(y); y0 = y0 > (HH - 2) ? (HH - 2) : y0;
    float wx = x - (float)x0;
    float wy = y - (float)y0;
    const float* p = pl + ((size_t)c << 14) + (y0 << 7) + x0;
    float top = p[0] * (1.f - wx) + p[1] * wx;
    float bot = p[WW] * (1.f - wx) + p[WW + 1] * wx;
    return top * (1.f - wy) + bot * wy;
}

__global__ __launch_bounds__(128) void equi_attn_cf_kernel(
    const float* __restrict__ qp, const float* __restrict__ cxz,
    const float* __restrict__ cxy, const float* __restrict__ cyz,
    const float* __restrict__ cp, const float* __restrict__ Wv,
    const float* __restrict__ bv, const float* __restrict__ Ww,
    const float* __restrict__ bw, const float* __restrict__ Wo,
    const float* __restrict__ bo, float* __restrict__ out, int ns)
{
    const int q = blockIdx.x, b = q / ns, tid = threadIdx.x;
    const size_t planeStride = (size_t)CCH * NPIX;
    const float* pxz = cxz + (size_t)b * planeStride;
    const float* pxy = cxy + (size_t)b * planeStride;
    const float* pyz = cyz + (size_t)b * planeStride;
    const float* qptr = qp + (size_t)q * 9;
    const float px = qptr[0], py = qptr[1], pz = qptr[2];
    const float a1x = qptr[3], a1y = qptr[4], a1z = qptr[5];
    const float a2x = qptr[6], a2y = qptr[7], a2z = qptr[8];
    float n1 = rsqrtf(a1x * a1x + a1y * a1y + a1z * a1z);
    float b1x = a1x * n1, b1y = a1y * n1, b1z = a1z * n1;
    float dd = b1x * a2x + b1y * a2y + b1z * a2z;
    float u2x = a2x - dd * b1x, u2y = a2y - dd * b1y, u2z = a2z - dd * b1z;
    float n2 = rsqrtf(u2x * u2x + u2y * u2y + u2z * u2z);
    float b2x = u2x * n2, b2y = u2y * n2, b2z = u2z * n2;
    float b3x = b1y * b2z - b1z * b2y;
    float b3y = b1z * b2x - b1x * b2z;
    float b3z = b1x * b2y - b1y * b2x;
    __shared__ float sFeat[CCH]; __shared__ float sW[32];
    __shared__ float sWsum[CCH]; __shared__ float sPre[CCH];
    float feat = bilin_cf(pxz, tid, px, pz) + bilin_cf(pxy, tid, px, py) + bilin_cf(pyz, tid, py, pz);
    sFeat[tid] = feat;
    __syncthreads();
    if (tid < NCP) {
        float acc = bw[tid];
        for (int c = 0; c < CCH; ++c) acc += sFeat[c] * Ww[c * NCP + tid];
        sW[tid] = acc;
    }
    __syncthreads();
    float sw = 0.f;
    #pragma unroll
    for (int g = 0; g < NCP; ++g) sw += sW[g];
    float wacc = 0.f;
    for (int g = 0; g < NCP; ++g) {
        float cx = cp[g * 3 + 0], cy = cp[g * 3 + 1], cz = cp[g * 3 + 2];
        float ax = px + b1x * cx + b1y * cy + b1z * cz;
        float ay = py + b2x * cx + b2y * cy + b2z * cz;
        float az = pz + b3x * cx + b3y * cy + b3z * cz;
        wacc += sW[g] * (bilin_cf(pxz, tid, ax, az) + bilin_cf(pxy, tid, ax, ay) + bilin_cf(pyz, tid, ay, az));
    }
    sWsum[tid] = wacc;
    __syncthreads();
    float pre = sw * bv[tid];
    for (int c = 0; c < CCH; ++c) pre += sWsum[c] * Wv[c * CCH + tid];
    sPre[tid] = pre;
    __syncthreads();
    float o = bo[tid] + feat;
    for (int h = 0; h < CCH; ++h) o += sPre[h] * Wo[h * CCH + tid];
    out[(size_t)q * CCH + tid] = o;
}

extern "C" void kernel_launch(void* const* d_in, const int* in_sizes, int n_in,
                              void* d_out, int out_size, void* d_ws, size_t ws_size,
                              hipStream_t stream) {
    const float* qp  = (const float*)d_in[0];
    const float* cxz = (const float*)d_in[1];
    const float* cxy = (const float*)d_in[2];
    const float* cyz = (const float*)d_in[3];
    const float* cp  = (const float*)d_in[4];
    const float* Wv  = (const float*)d_in[5];
    const float* bv  = (const float*)d_in[6];
    const float* Ww  = (const float*)d_in[7];
    const float* bw  = (const float*)d_in[8];
    const float* Wo  = (const float*)d_in[9];
    const float* bo  = (const float*)d_in[10];
    float* out = (float*)d_out;

    const int bs = in_sizes[1] / (CCH * NPIX);
    const int ns = in_sizes[0] / (bs * 9);
    const int nq = bs * ns;

    const size_t planeFloats = (size_t)bs * CCH * NPIX;     // per plane
    const size_t needBytes = 3 * planeFloats * sizeof(__half);

    if (ws_size >= needBytes && (nq % 16) == 0) {
        __half* t_xz = (__half*)d_ws;
        __half* t_xy = t_xz + planeFloats;
        __half* t_yz = t_xy + planeFloats;

        dim3 tgrid(NPIX / 64, CCH / 64, bs * 3);
        dim3 tblk(64, 4);
        transpose_f16_kernel<<<tgrid, tblk, 0, stream>>>(cxz, cxy, cyz, t_xz, t_xy, t_yz);

        equi_qpw4_kernel<<<nq / 16, 256, 0, stream>>>(
            qp, t_xz, t_xy, t_yz, cp, Wv, bv, Ww, bw, Wo, bo, out, ns);
    } else {
        equi_attn_cf_kernel<<<nq, 128, 0, stream>>>(
            qp, cxz, cxy, cyz, cp, Wv, bv, Ww, bw, Wo, bo, out, ns);
    }
}